// Round 16
// baseline (43.284 us; speedup 1.0000x reference)
//
#include <hip/hip_runtime.h>

#define Bq 2
#define Nq 1024
#define Cq 128
#define Eq 64
#define Kq 20
#define TI 4
#define BN (Bq * Nq)
#define BNK (BN * Kq)
#define NEGF (-3.0e38f)

#define DPP_F(x, ctrl) __int_as_float(__builtin_amdgcn_update_dpp( \
    __float_as_int(x), __float_as_int(x), (ctrl), 0xf, 0xf, false))
#define DPP_I(x, ctrl) __builtin_amdgcn_update_dpp((x), (x), (ctrl), 0xf, 0xf, false)
#define RL_F(x, l) __int_as_float(__builtin_amdgcn_readlane(__float_as_int(x), (l)))
#define RL_I(x, l) __builtin_amdgcn_readlane((x), (l))
#define QP_XOR1 0xB1   // quad_perm [1,0,3,2]
#define QP_XOR2 0x4E   // quad_perm [2,3,0,1]
#define ROR4    0x124  // row_ror:4
#define ROR8    0x128  // row_ror:8

// ---------------- proj: R11-exact (plain stores) ----------------
__global__ __launch_bounds__(128) void proj_kernel(
    const float* __restrict__ x, const float* __restrict__ Wl,
    const float* __restrict__ bl, const float* __restrict__ Wr,
    const float* __restrict__ br, const float* __restrict__ att,
    float* __restrict__ xl, float* __restrict__ xrP, float* __restrict__ rdot) {
  const int row = blockIdx.x;
  const int t = threadIdx.x;
  const int e = t & 63;
  const bool left = (t < 64);
  __shared__ float xs[Cq];
  xs[t] = x[(size_t)row * Cq + t];
  __syncthreads();
  const float* __restrict__ W = left ? Wl : Wr;
  float acc = 0.f;
#pragma unroll 8
  for (int c = 0; c < Cq; ++c) acc = fmaf(xs[c], W[c * Eq + e], acc);
  acc += left ? bl[e] : br[e];
  if (left) {
    xl[(size_t)row * Eq + e] = acc;
  } else {
    // plane-major: xrP[ch=e>>2][row][c=e&3]
    xrP[((size_t)(e >> 2) * BN + row) * 4 + (e & 3)] = acc;
    float s = acc * att[e];                 // rdot[row] = sum_e xr[row][e]*att[e]
    s += DPP_F(s, QP_XOR1);
    s += DPP_F(s, QP_XOR2);
    s += DPP_F(s, ROR4);
    s += DPP_F(s, ROR8);
    const float sd = (RL_F(s, 0) + RL_F(s, 16)) + (RL_F(s, 32) + RL_F(s, 48));
    if (e == 0) rdot[row] = sd;
  }
}

// ---------------- attn: R11 + per-WAVE desynchronization ----------------
// grid = BN/4 = 512 blocks, block = 512 (8 waves).
// Anti-lockstep: (a) each wave starts its plane sweep at a different phase,
// (b) each wave handles a rotated j-column slice (bijective; alpha stored at true j),
// (c) 2-ahead rotated pipeline (4 float4 in flight, static parity indices).
__global__ __launch_bounds__(512) void attn_kernel(
    const float* __restrict__ xl, const float* __restrict__ xrP,
    const float* __restrict__ rdot, const float* __restrict__ att,
    float* __restrict__ out) {
  const int r0g  = blockIdx.x * TI;
  const int b    = r0g >> 10;
  const int tid  = threadIdx.x;
  const int lane = tid & 63;
  const int wave = tid >> 6;

  __shared__ float alpha[TI][Nq];   // 16 KB

  // ---- phase 1: desynced sweep ----
  {
    // per-wave rotated j column (bijection within each 512-half)
    const int jcol  = (tid + ((wave & 3) << 7)) & 511;
    const int start = ((blockIdx.x << 1) + wave) & 15;      // per-WAVE plane phase
    const float* __restrict__ xlw = xl + (size_t)r0g * Eq;  // block-uniform -> s_load
    const size_t rowoff = ((size_t)b * Nq + jcol) * 4;

    const float rd0 = 1.5f * rdot[b * Nq + jcol];
    const float rd1 = 1.5f * rdot[b * Nq + jcol + 512];
    float acc[TI][2];
#pragma unroll
    for (int r = 0; r < TI; ++r) { acc[r][0] = rd0; acc[r][1] = rd1; }

    // 2-ahead rotated prefetch buffers (static indices under full unroll)
    float4 v0b[2], v1b[2];
#pragma unroll
    for (int k = 0; k < 2; ++k) {
      const int p = (start + k) & 15;
      const float* __restrict__ pa = xrP + (size_t)p * BN * 4 + rowoff;
      v0b[k] = *(const float4*)(pa);
      v1b[k] = *(const float4*)(pa + 512 * 4);
    }

#pragma unroll
    for (int i = 0; i < 16; ++i) {
      const int p = (start + i) & 15;
      const float4 v0 = v0b[i & 1];
      const float4 v1 = v1b[i & 1];
      if (i < 14) {                        // issue plane i+2 before computing plane i
        const int pn = (start + i + 2) & 15;
        const float* __restrict__ pa = xrP + (size_t)pn * BN * 4 + rowoff;
        v0b[i & 1] = *(const float4*)(pa);
        v1b[i & 1] = *(const float4*)(pa + 512 * 4);
      }
      const float4 at = *(const float4*)(att + p * 4);          // uniform -> s_load
      const float4 a0 = *(const float4*)(xlw + p * 4);          // uniform -> s_load
      const float4 a1 = *(const float4*)(xlw + Eq + p * 4);
      const float4 a2 = *(const float4*)(xlw + 2 * Eq + p * 4);
      const float4 a3 = *(const float4*)(xlw + 3 * Eq + p * 4);
      const float* v0p = (const float*)&v0;
      const float* v1p = (const float*)&v1;
      const float* a0p = (const float*)&a0;
      const float* a1p = (const float*)&a1;
      const float* a2p = (const float*)&a2;
      const float* a3p = (const float*)&a3;
      const float* atp = (const float*)&at;
#pragma unroll
      for (int dd = 0; dd < 4; ++dd) {
        const float a = atp[dd];
        const float x0 = v0p[dd], x1 = v1p[dd];
        acc[0][0] = fmaf(fabsf(a0p[dd] + x0), a, acc[0][0]);
        acc[0][1] = fmaf(fabsf(a0p[dd] + x1), a, acc[0][1]);
        acc[1][0] = fmaf(fabsf(a1p[dd] + x0), a, acc[1][0]);
        acc[1][1] = fmaf(fabsf(a1p[dd] + x1), a, acc[1][1]);
        acc[2][0] = fmaf(fabsf(a2p[dd] + x0), a, acc[2][0]);
        acc[2][1] = fmaf(fabsf(a2p[dd] + x1), a, acc[2][1]);
        acc[3][0] = fmaf(fabsf(a3p[dd] + x0), a, acc[3][0]);
        acc[3][1] = fmaf(fabsf(a3p[dd] + x1), a, acc[3][1]);
      }
    }
#pragma unroll
    for (int r = 0; r < TI; ++r) {
      alpha[r][jcol]       = acc[r][0];   // stored at TRUE j (bijection per half)
      alpha[r][jcol + 512] = acc[r][1];
    }
  }
  __syncthreads();

  // ---- phase 2: waves 0..3 = top-K of row `wave`, DPP-only reduces ----
  if (wave < TI) {
    float vals[16];
#pragma unroll
    for (int s = 0; s < 16; ++s) vals[s] = alpha[wave][lane + 64 * s];

    float lv = vals[0];
    int   pk = lane;                      // pk = (s<<6)|lane == j
#pragma unroll
    for (int s = 1; s < 16; ++s)
      if (vals[s] > lv) { lv = vals[s]; pk = (s << 6) | lane; }

    float m0 = 0.f, ssum = 0.f, myv = 0.f;
    int myi = 0;
#pragma unroll 1
    for (int round = 0; round < Kq; ++round) {
      float m = lv;
      m = fmaxf(m, DPP_F(m, QP_XOR1));
      m = fmaxf(m, DPP_F(m, QP_XOR2));
      m = fmaxf(m, DPP_F(m, ROR4));
      m = fmaxf(m, DPP_F(m, ROR8));
      const float bv = fmaxf(fmaxf(RL_F(m, 0), RL_F(m, 16)),
                             fmaxf(RL_F(m, 32), RL_F(m, 48)));
      int key = (lv == bv) ? pk : 0x7FFFFFFF;   // min-j tie-break (lax.top_k)
      key = min(key, DPP_I(key, QP_XOR1));
      key = min(key, DPP_I(key, QP_XOR2));
      key = min(key, DPP_I(key, ROR4));
      key = min(key, DPP_I(key, ROR8));
      const int jsel = min(min(RL_I(key, 0), RL_I(key, 16)),
                           min(RL_I(key, 32), RL_I(key, 48)));
      if (round == 0) m0 = bv;
      ssum += __expf(0.4f * (bv - m0));   // undo the /0.4 scaling here
      if (lane == round) { myv = bv; myi = jsel; }
      if (lane == (jsel & 63)) {          // owner knockout + rescan
        const int sk = jsel >> 6;
#pragma unroll
        for (int s = 0; s < 16; ++s)
          if (s == sk) vals[s] = NEGF;
        lv = vals[0]; pk = lane;
#pragma unroll
        for (int s = 1; s < 16; ++s)
          if (vals[s] > lv) { lv = vals[s]; pk = (s << 6) | lane; }
      }
    }

    if (lane < Kq) {
      const int gi = r0g + wave;
      const float p = __expf(0.4f * (myv - m0)) / ssum;
      const int base = gi * Kq + lane;
      out[base]            = (float)gi;              // index_i
      out[BNK + base]      = (float)(b * Nq + myi);  // index_j
      out[2 * BNK + base]  = p;                      // attention
    }
  }
}

extern "C" void kernel_launch(void* const* d_in, const int* in_sizes, int n_in,
                              void* d_out, int out_size, void* d_ws, size_t ws_size,
                              hipStream_t stream) {
  const float* x   = (const float*)d_in[0];
  const float* Wl  = (const float*)d_in[1];
  const float* bl  = (const float*)d_in[2];
  const float* Wr  = (const float*)d_in[3];
  const float* br  = (const float*)d_in[4];
  const float* att = (const float*)d_in[5];
  float* out = (float*)d_out;

  float* xl   = (float*)d_ws;                    // [B*N, E]
  float* xrP  = xl + (size_t)BN * Eq;            // [16][B*N][4] plane-major
  float* rdot = xrP + (size_t)16 * BN * 4;       // [B*N]

  proj_kernel<<<BN, 128, 0, stream>>>(x, Wl, bl, Wr, br, att, xl, xrP, rdot);
  attn_kernel<<<BN / TI, 512, 0, stream>>>(xl, xrP, rdot, att, out);
}